// Round 5
// baseline (142.585 us; speedup 1.0000x reference)
//
#include <hip/hip_runtime.h>

typedef unsigned short u16;
typedef unsigned int u32;
typedef short bf16x8 __attribute__((ext_vector_type(8)));
typedef float f32x4 __attribute__((ext_vector_type(4)));
typedef float f32x8v __attribute__((ext_vector_type(8)));
typedef float f32x16 __attribute__((ext_vector_type(16)));

#define LOG2E 1.44269504f

__device__ __forceinline__ u16 f2b(float f) {
  union { float f; unsigned u; } v; v.f = f;
  unsigned r = v.u + 0x7FFFu + ((v.u >> 16) & 1u);
  return (u16)(r >> 16);
}

__device__ __forceinline__ u32 pk2(float a, float b) {
  union { float f; u32 u; } x, y; x.f = a; y.f = b;
  return ((x.u + 0x8000u) >> 16) | ((y.u + 0x8000u) & 0xFFFF0000u);
}

__device__ __forceinline__ void plswap(u32& x, u32& y) {
#if __has_builtin(__builtin_amdgcn_permlane32_swap)
  typedef int v2i __attribute__((ext_vector_type(2)));
  v2i r = __builtin_amdgcn_permlane32_swap((int)x, (int)y, false, false);
  x = (u32)r[0]; y = (u32)r[1];
#else
  u32 sx = (u32)__shfl_xor((int)x, 32, 64);
  u32 sy = (u32)__shfl_xor((int)y, 32, 64);
  bool hi = (threadIdx.x & 63) >= 32;
  u32 nx = hi ? sy : x;
  u32 ny = hi ? y : sx;
  x = nx; y = ny;
#endif
}

// async global->LDS, 16B per lane; LDS dest must be wave-uniform base (HW adds lane*16)
__device__ __forceinline__ void gld16(const void* g, void* l) {
  __builtin_amdgcn_global_load_lds((const __attribute__((address_space(1))) void*)g,
                                   (__attribute__((address_space(3))) void*)l, 16, 0, 0);
}

// ---------------- cast x: fp32 -> bf16, 4 elems/thread ----------------
__global__ __launch_bounds__(256) void k_cast(const float* __restrict__ in, u16* __restrict__ out) {
  int i = blockIdx.x * 256 + threadIdx.x;
  float4 v = ((const float4*)in)[i];
  ushort4 o;
  o.x = f2b(v.x); o.y = f2b(v.y); o.z = f2b(v.z); o.w = f2b(v.w);
  ((ushort4*)out)[i] = o;
}

// ------------- transpose+cast weights: in[R][C] fp32 -> out[C][R] bf16 -------------
__global__ __launch_bounds__(256) void k_transpose(const float* __restrict__ in, u16* __restrict__ out,
                                                   int R, int C) {
  __shared__ float tile[32][33];
  int c0 = blockIdx.x * 32, r0 = blockIdx.y * 32;
  int tx = threadIdx.x, ty = threadIdx.y;
#pragma unroll
  for (int i = 0; i < 32; i += 8)
    tile[ty + i][tx] = in[(size_t)(r0 + ty + i) * C + c0 + tx];
  __syncthreads();
#pragma unroll
  for (int i = 0; i < 32; i += 8)
    out[(size_t)(c0 + ty + i) * R + r0 + tx] = f2b(tile[tx][ty + i]);
}

// ------------- GEMM: C[M][N] fp32 = A[M][K]bf16 * Bt[N][K]bf16^T, 128x128 tile -------------
template<int Nsz, int Ksz>
__global__ __launch_bounds__(256) void k_gemm_bt(const u16* __restrict__ A, const u16* __restrict__ Bt,
                                                 float* __restrict__ C) {
  __shared__ u16 As[128 * 32];
  __shared__ u16 Bs[128 * 32];
  const int tid = threadIdx.x;
  const int l = tid & 63, w = tid >> 6;
  const int wm = w >> 1, wn = w & 1;
  const int m0 = blockIdx.x * 128, n0 = blockIdx.y * 128;
  const int rg = l >> 4, cl = l & 15;
  f32x4 acc[4][4] = {};
  for (int k0 = 0; k0 < Ksz; k0 += 32) {
#pragma unroll
    for (int i = 0; i < 2; i++) {
      int c = tid + i * 256;
      int row = c >> 2, off = c & 3;
      uint4 va = *(const uint4*)(A + (size_t)(m0 + row) * Ksz + k0 + off * 8);
      uint4 vb = *(const uint4*)(Bt + (size_t)(n0 + row) * Ksz + k0 + off * 8);
      unsigned ba = (unsigned)((row * 64 + off * 16) ^ ((row & 7) << 4));
      *(uint4*)((char*)As + ba) = va;
      *(uint4*)((char*)Bs + ba) = vb;
    }
    __syncthreads();
    bf16x8 aF[4], bF[4];
#pragma unroll
    for (int m = 0; m < 4; m++) {
      int row = wm * 64 + m * 16 + cl;
      unsigned ba = (unsigned)((row * 64 + rg * 16) ^ ((row & 7) << 4));
      aF[m] = *(const bf16x8*)((char*)As + ba);
    }
#pragma unroll
    for (int n = 0; n < 4; n++) {
      int row = wn * 64 + n * 16 + cl;
      unsigned ba = (unsigned)((row * 64 + rg * 16) ^ ((row & 7) << 4));
      bF[n] = *(const bf16x8*)((char*)Bs + ba);
    }
#pragma unroll
    for (int m = 0; m < 4; m++)
#pragma unroll
      for (int n = 0; n < 4; n++)
        acc[m][n] = __builtin_amdgcn_mfma_f32_16x16x32_bf16(aF[m], bF[n], acc[m][n], 0, 0, 0);
    __syncthreads();
  }
#pragma unroll
  for (int m = 0; m < 4; m++)
#pragma unroll
    for (int n = 0; n < 4; n++)
#pragma unroll
      for (int r = 0; r < 4; r++)
        C[(size_t)(m0 + wm * 64 + m * 16 + rg * 4 + r) * Nsz + n0 + wn * 64 + n * 16 + cl] = acc[m][n][r];
}

// ------------- RoPE Q/K (vectorized x8); scatter to head-major bf16 (Q scaled by 1/8) -------------
__global__ __launch_bounds__(256) void k_rope(const float* __restrict__ qkv, const float* __restrict__ cs,
                                              const float* __restrict__ sn, u16* __restrict__ Qb,
                                              u16* __restrict__ Kb) {
  int idx = blockIdx.x * 256 + threadIdx.x;  // over 4096*192 8-elem chunks
  int c8 = idx % 192;
  int row = idx / 192;
  int c = c8 * 8;
  int b = row >> 11, t = row & 2047;
  int d = c & 63;
  const float* rp = qkv + (size_t)row * 2048;
  f32x8v x = *(const f32x8v*)(rp + c);
  int po = (d < 32) ? c + 32 : c - 32;
  float sgn = (d < 32) ? -1.f : 1.f;
  f32x8v xr = *(const f32x8v*)(rp + po);
  f32x8v cc = *(const f32x8v*)(cs + t * 64 + d);
  f32x8v ss = *(const f32x8v*)(sn + t * 64 + d);
  f32x8v val = x * cc + (xr * sgn) * ss;
  float scale = (c < 1024) ? 0.125f : 1.0f;
  uint4 ov;
  ov.x = pk2(val[0] * scale, val[1] * scale);
  ov.y = pk2(val[2] * scale, val[3] * scale);
  ov.z = pk2(val[4] * scale, val[5] * scale);
  ov.w = pk2(val[6] * scale, val[7] * scale);
  if (c < 1024) {
    int h = c >> 6;
    *(uint4*)(Qb + ((size_t)(b * 16 + h) * 2048 + t) * 64 + d) = ov;
  } else {
    int kk = (c - 1024) >> 6;
    *(uint4*)(Kb + ((size_t)(b * 8 + kk) * 2048 + t) * 64 + d) = ov;
  }
}

// ------------- V transpose: qkv fp32 V-part -> Vt[b*8+kh][64][2048] bf16 -------------
__global__ __launch_bounds__(256) void k_vtrans(const float* __restrict__ qkv, u16* __restrict__ Vt) {
  __shared__ u16 tile[64][65];
  int blk = blockIdx.x;
  int t0 = (blk & 31) * 64;
  int bh = blk >> 5;  // b*8+kh
  int tx = threadIdx.x & 63, ty = threadIdx.x >> 6;
  const float* src = qkv + (size_t)((bh >> 3) * 2048 + t0) * 2048 + 1536 + (bh & 7) * 64;
#pragma unroll
  for (int i = 0; i < 64; i += 4)
    tile[ty + i][tx] = f2b(src[(size_t)(ty + i) * 2048 + tx]);
  __syncthreads();
  u16* dst = Vt + (size_t)bh * 64 * 2048 + t0;
#pragma unroll
  for (int i = 0; i < 64; i += 4)
    dst[(size_t)(ty + i) * 2048 + tx] = tile[tx][ty + i];
}

// ------------- causal flash attention v5: 4-wave balanced blocks, LDS-staged K/V -------------
// block = (b, kh, g): 4 waves = 2 heads x qt in {2g, 2g+1}. All waves have trip count
// exactly NT = g+1 (QBLK=32, KVBLK=64 pairing) -> zero barrier idle. K/V double-buffered
// LDS via global_load_lds (pre-swizzled source chunks), counted vmcnt. T13 defer-max.
__global__ __launch_bounds__(256) void k_flash5(const u16* __restrict__ Qb, const u16* __restrict__ Kb,
                                                const u16* __restrict__ Vt, u16* __restrict__ Ob) {
  __shared__ u16 Ks[2][64 * 64];
  __shared__ u16 Vs[2][64 * 64];
  __shared__ u32 otile[4][32 * 36];
  const int tid = threadIdx.x;
  const int l = tid & 63, w = tid >> 6;
  const int bid = blockIdx.x;
  const int bkh = bid & 15, g = 31 - (bid >> 4);   // kh fastest (XCD L2 pinning), g descending (LPT)
  const int b = bkh >> 3, kh = bkh & 7;
  const int h = kh * 2 + (w & 1);
  const int qt = 2 * g + (w >> 1);
  const int q0 = qt * 32;
  const int lq = l & 31, hi = l >> 5;
  const int q = q0 + lq;
  const int xr = lq & 7;
  const int NT = g + 1;

  const u16* Kg = Kb + (size_t)(b * 8 + kh) * 2048 * 64;
  const u16* Vg = Vt + (size_t)(b * 8 + kh) * 64 * 2048;
  const u16* Qp = Qb + ((size_t)(b * 16 + h) * 2048 + q) * 64 + hi * 8;

  // staging decode: 256 threads x 16B x 2 calls = 8KB tile; source chunk pre-swizzled
  const int sr = tid >> 3;          // 0..31
  const int sc0 = tid & 7;

#define STAGE(buf, t)                                                                   \
  {                                                                                     \
    const int kvb_ = (t) << 6;                                                          \
    _Pragma("unroll")                                                                   \
    for (int c = 0; c < 2; c++) {                                                       \
      int row = c * 32 + sr;                                                            \
      int ch = sc0 ^ (row & 7);                                                         \
      gld16(Kg + (size_t)(kvb_ + row) * 64 + ch * 8, &Ks[buf][(c * 32 + w * 8) * 64]);  \
    }                                                                                   \
    _Pragma("unroll")                                                                   \
    for (int c = 0; c < 2; c++) {                                                       \
      int row = c * 32 + sr;                                                            \
      int ch = sc0 ^ (row & 7);                                                         \
      gld16(Vg + (size_t)row * 2048 + kvb_ + ch * 8, &Vs[buf][(c * 32 + w * 8) * 64]);  \
    }                                                                                   \
  }

  STAGE(0, 0);

  bf16x8 qf[4];
#pragma unroll
  for (int ks = 0; ks < 4; ks++) qf[ks] = *(const bf16x8*)(Qp + ks * 16);

  f32x16 oa[2] = {};
  float m = -3e38f, lsum = 0.f;

  for (int t = 0; t < NT; t++) {
    const int cur = t & 1;
    if (t + 1 < NT) {
      STAGE(cur ^ 1, t + 1);
      asm volatile("s_waitcnt vmcnt(4)" ::: "memory");
    } else {
      asm volatile("s_waitcnt vmcnt(0)" ::: "memory");
    }
    __builtin_amdgcn_s_barrier();
    asm volatile("" ::: "memory");

    const int kvb = t << 6;
    const u16* KL = Ks[cur];
    const u16* VL = Vs[cur];
    // K fragments (swizzled chunks; rows lq and lq+32 share lq&7)
    bf16x8 kf0[4], kf1[4];
#pragma unroll
    for (int ks = 0; ks < 4; ks++) {
      int cc = (((ks << 1) | hi) ^ xr) * 8;
      kf0[ks] = *(const bf16x8*)(KL + lq * 64 + cc);
      kf1[ks] = *(const bf16x8*)(KL + (lq + 32) * 64 + cc);
    }
    f32x16 s0 = {}, s1 = {};
    __builtin_amdgcn_s_setprio(1);
#pragma unroll
    for (int ks = 0; ks < 4; ks++) {
      s0 = __builtin_amdgcn_mfma_f32_32x32x16_bf16(kf0[ks], qf[ks], s0, 0, 0, 0);
      s1 = __builtin_amdgcn_mfma_f32_32x32x16_bf16(kf1[ks], qf[ks], s1, 0, 0, 0);
    }
    __builtin_amdgcn_s_setprio(0);

    // V fragments issued before softmax (LDS latency hides under VALU)
    bf16x8 vf[2][2][2];
#pragma unroll
    for (int dt = 0; dt < 2; dt++)
#pragma unroll
      for (int n = 0; n < 2; n++)
#pragma unroll
        for (int s16 = 0; s16 < 2; s16++) {
          int cc = ((n * 4 + s16 * 2 + hi) ^ xr) * 8;
          vf[dt][n][s16] = *(const bf16x8*)(VL + (dt * 32 + lq) * 64 + cc);
        }

    // causal mask (diagonal tile = last tile of every wave)
    if (t == NT - 1) {
#pragma unroll
      for (int r = 0; r < 16; r++) {
        int kvr = kvb + (r & 3) + 8 * (r >> 2) + 4 * hi;
        if (kvr > q) s0[r] = -3e38f;
        if (kvr + 32 > q) s1[r] = -3e38f;
      }
    }

    // online softmax; T13 defer-max when per-tile max growth <= 8
    float tr[16];
#pragma unroll
    for (int r = 0; r < 16; r++) tr[r] = fmaxf(s0[r], s1[r]);
#pragma unroll
    for (int i = 0; i < 5; i++) tr[i] = fmaxf(fmaxf(tr[3 * i], tr[3 * i + 1]), tr[3 * i + 2]);
    tr[0] = fmaxf(fmaxf(tr[0], tr[1]), tr[2]);
    tr[0] = fmaxf(fmaxf(tr[0], tr[3]), fmaxf(tr[4], tr[15]));
    float mx = fmaxf(tr[0], __shfl_xor(tr[0], 32, 64));
    bool keep = __all(mx - m <= 8.f);
    float mnew = keep ? m : fmaxf(m, mx);
    float alpha = keep ? 1.f : exp2f((m - mnew) * LOG2E);
    m = mnew;
    float mb = m * LOG2E;
#pragma unroll
    for (int r = 0; r < 16; r++) {
      s0[r] = exp2f(fmaf(s0[r], LOG2E, -mb));
      s1[r] = exp2f(fmaf(s1[r], LOG2E, -mb));
    }
#pragma unroll
    for (int r = 0; r < 16; r++) tr[r] = s0[r] + s1[r];
#pragma unroll
    for (int st = 8; st >= 1; st >>= 1)
#pragma unroll
      for (int i = 0; i < st; i++) tr[i] += tr[i + st];
    float ssum = tr[0] + __shfl_xor(tr[0], 32, 64);
    if (!keep) {
      lsum *= alpha;
#pragma unroll
      for (int r = 0; r < 16; r++) { oa[0][r] *= alpha; oa[1][r] *= alpha; }
    }
    lsum += ssum;

    // P -> bf16 B-fragments (pk2 + permlane32_swap), then PV: O^T += V^T . P
#pragma unroll
    for (int n = 0; n < 2; n++) {
      u32 aw[8];
#pragma unroll
      for (int j = 0; j < 8; j++) {
        float va = n ? s1[2 * j] : s0[2 * j];
        float vb = n ? s1[2 * j + 1] : s0[2 * j + 1];
        aw[j] = pk2(va, vb);
      }
      plswap(aw[0], aw[2]); plswap(aw[1], aw[3]);
      plswap(aw[4], aw[6]); plswap(aw[5], aw[7]);
      union { u32 uu[4]; bf16x8 v; } p0, p1;
#pragma unroll
      for (int j = 0; j < 4; j++) { p0.uu[j] = aw[j]; p1.uu[j] = aw[4 + j]; }
      __builtin_amdgcn_s_setprio(1);
#pragma unroll
      for (int dt = 0; dt < 2; dt++) {
        oa[dt] = __builtin_amdgcn_mfma_f32_32x32x16_bf16(vf[dt][n][0], p0.v, oa[dt], 0, 0, 0);
        oa[dt] = __builtin_amdgcn_mfma_f32_32x32x16_bf16(vf[dt][n][1], p1.v, oa[dt], 0, 0, 0);
      }
      __builtin_amdgcn_s_setprio(0);
    }

    asm volatile("" ::: "memory");
    __builtin_amdgcn_s_barrier();
  }

  // ---- epilogue: normalize, transpose O^T -> O via wave-private LDS, coalesced store ----
  float linv = 1.0f / lsum;
  u32* ot = otile[w];
#pragma unroll
  for (int dt = 0; dt < 2; dt++)
#pragma unroll
    for (int r = 0; r < 16; r += 2) {
      int d = dt * 32 + (r & 3) + 8 * (r >> 2) + 4 * hi;
      ot[lq * 36 + (d >> 1)] =
          (u32)f2b(oa[dt][r] * linv) | ((u32)f2b(oa[dt][r + 1] * linv) << 16);
    }
  const u32* otr = otile[w];
#pragma unroll
  for (int i = 0; i < 16; i++) {
    int wd = i * 64 + l;
    int row = wd >> 5, col = wd & 31;
    u32 v = otr[row * 36 + col];
    *(u32*)(Ob + (size_t)(b * 2048 + q0 + row) * 1024 + h * 64 + col * 2) = v;
  }
}

extern "C" void kernel_launch(void* const* d_in, const int* in_sizes, int n_in,
                              void* d_out, int out_size, void* d_ws, size_t ws_size,
                              hipStream_t stream) {
  const float* x = (const float*)d_in[0];
  const float* cs = (const float*)d_in[1];
  const float* sn = (const float*)d_in[2];
  const float* w_qkv = (const float*)d_in[3];
  const float* w_out = (const float*)d_in[4];
  float* out = (float*)d_out;
  char* ws = (char*)d_ws;

  u16* Xb   = (u16*)(ws + (size_t)(0u) );          // 8 MB  [4096][1024]
  u16* Wqt  = (u16*)(ws + ((size_t)8u << 20));     // 4 MB  [2048][1024]
  u16* Wot  = (u16*)(ws + ((size_t)12u << 20));    // 2 MB  [1024][1024]
  float* qkv = (float*)(ws + ((size_t)14u << 20)); // 32 MB [4096][2048]
  u16* Qb   = (u16*)(ws + ((size_t)46u << 20));    // 8 MB  [2][16][2048][64]
  u16* Kb   = (u16*)(ws + ((size_t)54u << 20));    // 4 MB  [2][8][2048][64]
  u16* Vt   = (u16*)(ws + ((size_t)58u << 20));    // 4 MB  [2][8][64][2048]
  u16* Ob   = (u16*)(ws + ((size_t)62u << 20));    // 8 MB  [4096][1024]

  k_cast<<<4096, 256, 0, stream>>>(x, Xb);
  k_transpose<<<dim3(2048 / 32, 1024 / 32), dim3(32, 8), 0, stream>>>(w_qkv, Wqt, 1024, 2048);
  k_transpose<<<dim3(1024 / 32, 1024 / 32), dim3(32, 8), 0, stream>>>(w_out, Wot, 1024, 1024);
  k_gemm_bt<2048, 1024><<<dim3(32, 16), 256, 0, stream>>>(Xb, Wqt, qkv);
  k_rope<<<3072, 256, 0, stream>>>(qkv, cs, sn, Qb, Kb);
  k_vtrans<<<512, 256, 0, stream>>>(qkv, Vt);
  k_flash5<<<512, 256, 0, stream>>>(Qb, Kb, Vt, Ob);
  k_gemm_bt<1024, 1024><<<dim3(32, 8), 256, 0, stream>>>(Ob, Wot, out);
}